// Round 1
// baseline (551.773 us; speedup 1.0000x reference)
//
#include <hip/hip_runtime.h>
#include <hip/hip_bf16.h>

// ProcessContinuous: out[b,m, d*4+k] with k = {0:pot, 1:call, 2:stack, 3:odds}
//   emb_X[d] = relu(scalar_X * X_w[d] + X_b[d])
//   scalars: hero_stack = x[...,0], amnt_to_call = x[...,5], pot_odds = x[...,6]
// Memory-bound (537 MB of stores vs 17 MB of loads). One 128-thread group per
// row; thread d keeps all 8 weights in registers and emits one float4 per row.

#define C_DIM 16
#define D_DIM 128

__global__ __launch_bounds__(256) void ProcessContinuous_30786325577969_kernel(
    const float* __restrict__ x,
    const float* __restrict__ stack_w, const float* __restrict__ stack_b,
    const float* __restrict__ call_w,  const float* __restrict__ call_b,
    const float* __restrict__ odds_w,  const float* __restrict__ odds_b,
    const float* __restrict__ pot_w,   const float* __restrict__ pot_b,
    float4* __restrict__ out, int nrows)
{
    const int d = threadIdx.x & (D_DIM - 1);

    // Per-thread weights live in registers for the whole grid-stride loop.
    const float sw = stack_w[d], sb = stack_b[d];
    const float cw = call_w[d],  cb = call_b[d];
    const float ow = odds_w[d],  ob = odds_b[d];
    const float pw = pot_w[d],   pb = pot_b[d];

    const int rowsPerBlock = blockDim.x >> 7;                 // 2 for 256 threads
    int row    = blockIdx.x * rowsPerBlock + (threadIdx.x >> 7);
    const int stride = gridDim.x * rowsPerBlock;

    for (; row < nrows; row += stride) {
        const float* xr = x + (size_t)row * C_DIM;
        const float hero_stack   = xr[0];   // uniform across the 128-thread group
        const float amnt_to_call = xr[5];
        const float pot_odds     = xr[6];

        float4 v;
        v.x = fmaxf(fmaf(pot_odds,     pw, pb), 0.0f);  // emb_pot
        v.y = fmaxf(fmaf(amnt_to_call, cw, cb), 0.0f);  // emb_call
        v.z = fmaxf(fmaf(hero_stack,   sw, sb), 0.0f);  // emb_stack
        v.w = fmaxf(fmaf(pot_odds,     ow, ob), 0.0f);  // emb_odds

        out[(size_t)row * D_DIM + d] = v;               // coalesced 16 B/lane
    }
}

extern "C" void kernel_launch(void* const* d_in, const int* in_sizes, int n_in,
                              void* d_out, int out_size, void* d_ws, size_t ws_size,
                              hipStream_t stream) {
    const float* x       = (const float*)d_in[0];
    const float* stack_w = (const float*)d_in[1];
    const float* stack_b = (const float*)d_in[2];
    const float* call_w  = (const float*)d_in[3];
    const float* call_b  = (const float*)d_in[4];
    const float* odds_w  = (const float*)d_in[5];
    const float* odds_b  = (const float*)d_in[6];
    const float* pot_w   = (const float*)d_in[7];
    const float* pot_b   = (const float*)d_in[8];

    const int nrows = in_sizes[0] / C_DIM;   // B*M = 262144

    const int block = 256;                   // 2 rows per block-iteration
    int grid = 2048;                         // grid-stride; ~64 iters/block
    const int rowPairs = (nrows + 1) / 2;
    if (grid > rowPairs) grid = rowPairs;

    ProcessContinuous_30786325577969_kernel<<<grid, block, 0, stream>>>(
        x, stack_w, stack_b, call_w, call_b, odds_w, odds_b, pot_w, pot_b,
        (float4*)d_out, nrows);
}